// Round 9
// baseline (65.282 us; speedup 1.0000x reference)
//
#include <hip/hip_runtime.h>
#include <math.h>

// ---------------------------------------------------------------------------
// ZBL repulsion, R9: CSR / wave-per-atom (idx_i sorted -> segment bounds).
//  - k0: per atom: z8 (u8 Z), seg init {0,0}
//  - k1: per pair: run-boundary detect -> seg[a] = {start, end}
//  - k2: ONE WAVE PER ATOM: lanes cover the atom's contiguous run
//        (coalesced), per-lane private accumulate, ONE butterfly + ONE
//        plain store per atom. No atomics. No per-iteration shuffles.
//        idx_i not read at all. Epilogue (mask/clip/*0.01) folded in.
//  - 256-thread blocks, 1 KB LDS za table -> full occupancy for TLP
//  - native exp2/rcp/rsq lean math (validated absmax 2.4e-4)
// ---------------------------------------------------------------------------

#define LOG2E 1.4426950408889634f

static __device__ __forceinline__ float rcpf_(float x)  { return __builtin_amdgcn_rcpf(x); }
static __device__ __forceinline__ float rsqf_(float x)  { return __builtin_amdgcn_rsqf(x); }
static __device__ __forceinline__ float exp2f_(float x) { return __builtin_amdgcn_exp2f(x); }
static __device__ __forceinline__ float log2f_(float x) { return __builtin_amdgcn_logf(x); }

__global__ void zbl_k0(const float* __restrict__ an,
                       unsigned char* __restrict__ z8,
                       int2* __restrict__ seg, int n) {
    int i = blockIdx.x * blockDim.x + threadIdx.x;
    if (i >= n) return;
    int z = (int)(an[i] + 0.5f);
    z8[i] = (unsigned char)min(max(z, 1), 255);
    seg[i] = make_int2(0, 0);
}

__global__ void zbl_k1(const int* __restrict__ idx_i,
                       int2* __restrict__ seg, int nP) {
    int p = blockIdx.x * blockDim.x + threadIdx.x;
    if (p >= nP) return;
    int a    = idx_i[p];
    int prev = (p == 0)      ? -1 : idx_i[p - 1];
    int next = (p == nP - 1) ? -1 : idx_i[p + 1];
    int* sa = (int*)&seg[a];
    if (prev != a) sa[0] = p;        // run head -> start
    if (next != a) sa[1] = p + 1;    // run tail -> end
}

__global__ __launch_bounds__(256) void zbl_k2(
    const float* __restrict__ disp,        // [P*3]
    const int*   __restrict__ idx_j,
    const float* __restrict__ batch_mask,  // [P]
    const unsigned char* __restrict__ z8,  // [N]
    const int2*  __restrict__ seg,         // [N] {start,end}
    const float* __restrict__ atom_mask,   // [N]
    const float* __restrict__ a_coef_ptr,
    const float* __restrict__ a_exp_ptr,
    const float* __restrict__ phi_c,
    const float* __restrict__ phi_e,
    float* __restrict__ out,               // [N] final output
    int nA)
{
    __shared__ float s_za[256];
    const int tid = threadIdx.x;

    // build za table: za(z) = z^|a_exp|
    {
        float ae = fabsf(a_exp_ptr[0]);
        int z = max(tid, 1);
        s_za[tid] = exp2f_(ae * log2f_((float)z));
    }
    __syncthreads();

    const int lane = tid & 63;
    const int a = blockIdx.x * 4 + (tid >> 6);   // one wave per atom
    if (a >= nA) return;

    // per-thread uniforms
    const float ac_inv = rcpf_(fmaxf(fabsf(a_coef_ptr[0]), 1e-10f));
    float c0 = fabsf(phi_c[0]), c1 = fabsf(phi_c[1]);
    float c2 = fabsf(phi_c[2]), c3 = fabsf(phi_c[3]);
    const float cinv = rcpf_(fmaxf(c0 + c1 + c2 + c3, 1e-10f));
    c0 *= cinv; c1 *= cinv; c2 *= cinv; c3 *= cinv;
    const float e0 = fmaxf(fabsf(phi_e[0]), 1e-10f);
    const float e1 = fmaxf(fabsf(phi_e[1]), 1e-10f);
    const float e2 = fmaxf(fabsf(phi_e[2]), 1e-10f);
    const float e3 = fmaxf(fabsf(phi_e[3]), 1e-10f);

    const int2 se   = seg[a];
    const int  zi   = (int)z8[a];
    const float za_i = s_za[zi];
    const float zif  = (float)zi;

    float acc = 0.0f;
    for (int p0 = se.x; p0 < se.y; p0 += 64) {
        const int p = p0 + lane;
        if (p < se.y) {
            const int   jj = idx_j[p];
            const float bm = batch_mask[p];
            const int   zj = (int)z8[jj];
            const float za_j = s_za[zj];
            const float* dp = disp + (long)p * 3;
            const float add = 1.0f - bm;
            const float dx = dp[0] + add, dy = dp[1] + add, dz = dp[2] + add;

            float d2   = fmaxf(dx * dx + dy * dy + dz * dz, 1e-20f);
            float rsq  = rsqf_(d2);
            float dist = d2 * rsq;                  // sqrt(d2); 1/dist == rsq

            float tt = dist * 0.1f;
            float tc = fminf(fmaxf(tt, 1e-9f), 1.0f - 1e-9f);
            float u  = (1.0f - 2.0f * tc) * rcpf_(tc - tc * tc);
            float s  = rcpf_(1.0f + exp2f_(u * LOG2E));
            float sw = (tt >= 1.0f) ? 1.0f : s;

            float za_sum = za_i + za_j;
            float arg  = fminf(dist * za_sum * ac_inv, 1e6f);
            float narg = -arg * LOG2E;
            float phi  = c0 * exp2f_(e0 * narg) + c1 * exp2f_(e1 * narg) +
                         c2 * exp2f_(e2 * narg) + c3 * exp2f_(e3 * narg);
            phi = fminf(fmaxf(phi, 1e-30f), 1e6f);

            float cp   = fminf(zif * (float)zj, 1e4f);
            float brep = fminf(0.5f * cp * rsq, 1e6f);
            float r    = brep * phi * fmaxf(sw, 1e-30f);
            r = fminf(fmaxf(r, 0.0f), 1e6f);
            if (!(r == r)) r = 0.0f;
            acc += r * bm;
        }
    }

    // one butterfly per atom
    #pragma unroll
    for (int d = 1; d < 64; d <<= 1) acc += __shfl_xor(acc, d);

    if (lane == 0) {
        float v = acc * atom_mask[a];
        v = fminf(fmaxf(v, 0.0f), 1e6f);
        if (!(v == v)) v = 0.0f;
        out[a] = v * 0.01f;
    }
}

extern "C" void kernel_launch(void* const* d_in, const int* in_sizes, int n_in,
                              void* d_out, int out_size, void* d_ws, size_t ws_size,
                              hipStream_t stream) {
    const float* an         = (const float*)d_in[0];
    const float* disp       = (const float*)d_in[1];
    const int*   idx_i      = (const int*)d_in[2];
    const int*   idx_j      = (const int*)d_in[3];
    const float* atom_mask  = (const float*)d_in[4];
    const float* batch_mask = (const float*)d_in[5];
    const float* a_coef     = (const float*)d_in[8];
    const float* a_exp      = (const float*)d_in[9];
    const float* phi_c      = (const float*)d_in[10];
    const float* phi_e      = (const float*)d_in[11];

    const int nA = in_sizes[0];
    const int nP = in_sizes[2];
    float* out = (float*)d_out;

    // ws layout: seg (int2[nA], 800 KB) | z8 (u8[nA], 100 KB)
    int2* seg = (int2*)d_ws;
    unsigned char* z8 = (unsigned char*)((char*)d_ws + (size_t)nA * sizeof(int2));

    zbl_k0<<<(nA + 255) / 256, 256, 0, stream>>>(an, z8, seg, nA);
    zbl_k1<<<(nP + 255) / 256, 256, 0, stream>>>(idx_i, seg, nP);
    zbl_k2<<<(nA + 3) / 4, 256, 0, stream>>>(
        disp, idx_j, batch_mask, z8, seg, atom_mask,
        a_coef, a_exp, phi_c, phi_e, out, nA);
}

// Round 10
// 45.123 us; speedup vs baseline: 1.4467x; 1.4467x over previous
//
#include <hip/hip_runtime.h>
#include <math.h>

// ---------------------------------------------------------------------------
// ZBL repulsion, R10: R8 skeleton + depth-3 / unroll-2 register pipeline.
//  - persistent 1024-thr blocks (1/CU), LDS z8 (100 KB) + za[256] tables,
//    barrier-free main loop, wave scan + head atomics (sorted idx_i)
//  - loads issued 2 iterations ahead (counted-vmcnt pattern: compute only
//    waits on oldest loads), 2 independent 64-pair groups per iteration
//    -> 12 loads in flight per stage, 4x the MLP of R8
//  - native exp2/rcp/rsq lean math (validated absmax 2.4e-4)
// ---------------------------------------------------------------------------

#define LOG2E 1.4426950408889634f
#define BLK   1024
#define NBLK  256
#define STRD  (2 * BLK)              // pairs consumed per wave-iteration step

static __device__ __forceinline__ float rcpf_(float x)  { return __builtin_amdgcn_rcpf(x); }
static __device__ __forceinline__ float rsqf_(float x)  { return __builtin_amdgcn_rsqf(x); }
static __device__ __forceinline__ float exp2f_(float x) { return __builtin_amdgcn_exp2f(x); }
static __device__ __forceinline__ float log2f_(float x) { return __builtin_amdgcn_logf(x); }

struct f3 { float x, y, z; };
struct G  { int ii, jj; float bm, dx, dy, dz; };

__global__ void zbl_k0(const float* __restrict__ an,
                       unsigned char* __restrict__ z8,
                       float* __restrict__ out, int n) {
    int i = blockIdx.x * blockDim.x + threadIdx.x;
    if (i >= n) return;
    int z = (int)(an[i] + 0.5f);
    z8[i] = (unsigned char)min(max(z, 1), 255);
    out[i] = 0.0f;                       // d_out zeroing folded in
}

static __device__ __forceinline__ G loadG(const int* __restrict__ idx_i,
                                          const int* __restrict__ idx_j,
                                          const float* __restrict__ bmk,
                                          const float* __restrict__ disp,
                                          int p, int cend) {
    G g; g.ii = -1; g.jj = 0; g.bm = 0.0f; g.dx = 0.0f; g.dy = 0.0f; g.dz = 0.0f;
    if (p < cend) {
        g.ii = idx_i[p];
        g.jj = idx_j[p];
        g.bm = bmk[p];
        f3 d = *reinterpret_cast<const f3*>(disp + (long)p * 3);
        g.dx = d.x; g.dy = d.y; g.dz = d.z;
    }
    return g;
}

__global__ __launch_bounds__(BLK) void zbl_pair_kernel(
    const float* __restrict__ disp,
    const int*   __restrict__ idx_i,       // sorted
    const int*   __restrict__ idx_j,
    const float* __restrict__ batch_mask,
    const unsigned char* __restrict__ z8g,
    const float* __restrict__ a_coef_ptr,
    const float* __restrict__ a_exp_ptr,
    const float* __restrict__ phi_c,
    const float* __restrict__ phi_e,
    float* __restrict__ out_acc,           // [N] zeroed accumulator
    int nA, int nP)
{
    extern __shared__ unsigned char smem[];
    const int nA_pad = (nA + 15) & ~15;
    unsigned char* s_z8 = smem;                     // nA_pad bytes
    float*         s_za = (float*)(smem + nA_pad);  // 256 floats

    const int tid = threadIdx.x;

    // one-time: z8 table (coalesced uint4) + za table
    {
        const int nw = nA >> 4;
        const uint4* g4 = reinterpret_cast<const uint4*>(z8g);
        uint4* s4 = reinterpret_cast<uint4*>(s_z8);
        for (int i = tid; i < nw; i += BLK) s4[i] = g4[i];
        for (int i = (nw << 4) + tid; i < nA; i += BLK) s_z8[i] = z8g[i];
    }
    if (tid < 256) {
        float ae = fabsf(a_exp_ptr[0]);
        int z = max(tid, 1);
        s_za[tid] = exp2f_(ae * log2f_((float)z));   // z^|ae|
    }
    __syncthreads();                                  // the only barrier

    // per-thread uniforms
    const float ac_inv = rcpf_(fmaxf(fabsf(a_coef_ptr[0]), 1e-10f));
    float c0 = fabsf(phi_c[0]), c1 = fabsf(phi_c[1]);
    float c2 = fabsf(phi_c[2]), c3 = fabsf(phi_c[3]);
    const float cinv = rcpf_(fmaxf(c0 + c1 + c2 + c3, 1e-10f));
    c0 *= cinv; c1 *= cinv; c2 *= cinv; c3 *= cinv;
    const float e0 = fmaxf(fabsf(phi_e[0]), 1e-10f);
    const float e1 = fmaxf(fabsf(phi_e[1]), 1e-10f);
    const float e2 = fmaxf(fabsf(phi_e[2]), 1e-10f);
    const float e3 = fmaxf(fabsf(phi_e[3]), 1e-10f);

    const int chunk = (nP + NBLK - 1) / NBLK;
    const int cbeg  = blockIdx.x * chunk;
    const int cend  = min(cbeg + chunk, nP);
    const int lane  = tid & 63;

#define COMPUTE_G(g, rep, key)                                                  \
    {                                                                           \
        rep = 0.0f; key = -1;                                                   \
        if ((g).ii >= 0) {                                                      \
            const int zi = (int)s_z8[(g).ii];                                   \
            const int zj = (int)s_z8[(g).jj];                                   \
            const float za_i = s_za[zi];                                        \
            const float za_j = s_za[zj];                                        \
            const float add = 1.0f - (g).bm;                                    \
            const float dx = (g).dx + add, dy = (g).dy + add, dz = (g).dz + add;\
            float d2   = fmaxf(dx * dx + dy * dy + dz * dz, 1e-20f);            \
            float rsq  = rsqf_(d2);                                             \
            float dist = d2 * rsq;                                              \
            float tt = dist * 0.1f;                                             \
            float tc = fminf(fmaxf(tt, 1e-9f), 1.0f - 1e-9f);                   \
            float u  = (1.0f - 2.0f * tc) * rcpf_(tc - tc * tc);                \
            float s  = rcpf_(1.0f + exp2f_(u * LOG2E));                         \
            float sw = (tt >= 1.0f) ? 1.0f : s;                                 \
            float za_sum = za_i + za_j;                                         \
            float arg  = fminf(dist * za_sum * ac_inv, 1e6f);                   \
            float narg = -arg * LOG2E;                                          \
            float phi  = c0 * exp2f_(e0 * narg) + c1 * exp2f_(e1 * narg) +      \
                         c2 * exp2f_(e2 * narg) + c3 * exp2f_(e3 * narg);       \
            phi = fminf(fmaxf(phi, 1e-30f), 1e6f);                              \
            float cp   = fminf((float)(zi * zj), 1e4f);                         \
            float brep = fminf(0.5f * cp * rsq, 1e6f);                          \
            float r    = brep * phi * fmaxf(sw, 1e-30f);                        \
            r = fminf(fmaxf(r, 0.0f), 1e6f);                                    \
            if (!(r == r)) r = 0.0f;                                            \
            rep = r * (g).bm;                                                   \
            key = (g).ii;                                                       \
        }                                                                       \
    }

#define REDUCE_G(rep, key)                                                      \
    {                                                                           \
        const int k0_ = __shfl(key, 0);                                         \
        if (__all(key == k0_)) {                                                \
            float v = rep;                                                      \
            _Pragma("unroll")                                                   \
            for (int d = 1; d < 64; d <<= 1) v += __shfl_xor(v, d);             \
            if (lane == 0 && k0_ >= 0) atomicAdd(&out_acc[k0_], v);             \
        } else {                                                                \
            float v = rep;                                                      \
            int   k = key;                                                      \
            _Pragma("unroll")                                                   \
            for (int d = 1; d < 64; d <<= 1) {                                  \
                float nv = __shfl_down(v, d);                                   \
                int   nk = __shfl_down(k, d);                                   \
                if (lane + d < 64 && nk == k) v += nv;                          \
            }                                                                   \
            int pk = __shfl_up(k, 1);                                           \
            bool head = (lane == 0) || (pk != k);                               \
            if (head && k >= 0) atomicAdd(&out_acc[k], v);                      \
        }                                                                       \
    }

    // ---- depth-3 / unroll-2 pipeline: stages t, t+1, t+2 in registers
    G a0 = loadG(idx_i, idx_j, batch_mask, disp, cbeg + tid,            cend);
    G b0 = loadG(idx_i, idx_j, batch_mask, disp, cbeg + BLK + tid,      cend);
    G a1 = loadG(idx_i, idx_j, batch_mask, disp, cbeg + STRD + tid,     cend);
    G b1 = loadG(idx_i, idx_j, batch_mask, disp, cbeg + STRD + BLK + tid, cend);

    for (int pb = cbeg; pb < cend; pb += STRD) {
        // A) issue stage t+2 loads (12 loads; compute below only waits on
        //    the oldest stage's loads -> counted-vmcnt behavior)
        G a2 = loadG(idx_i, idx_j, batch_mask, disp, pb + 2 * STRD + tid,       cend);
        G b2 = loadG(idx_i, idx_j, batch_mask, disp, pb + 2 * STRD + BLK + tid, cend);

        // B) compute + reduce the two independent groups of stage t
        float repA, repB; int keyA, keyB;
        COMPUTE_G(a0, repA, keyA);
        COMPUTE_G(b0, repB, keyB);
        REDUCE_G(repA, keyA);
        REDUCE_G(repB, keyB);

        // C) rotate stages
        a0 = a1; b0 = b1; a1 = a2; b1 = b2;
    }
#undef COMPUTE_G
#undef REDUCE_G
}

__global__ void zbl_epilogue(float* __restrict__ out,
                             const float* __restrict__ atom_mask, int n) {
    int i = blockIdx.x * blockDim.x + threadIdx.x;
    if (i >= n) return;
    float v = out[i] * atom_mask[i];
    v = fminf(fmaxf(v, 0.0f), 1e6f);
    if (!(v == v)) v = 0.0f;
    out[i] = v * 0.01f;
}

extern "C" void kernel_launch(void* const* d_in, const int* in_sizes, int n_in,
                              void* d_out, int out_size, void* d_ws, size_t ws_size,
                              hipStream_t stream) {
    const float* an         = (const float*)d_in[0];
    const float* disp       = (const float*)d_in[1];
    const int*   idx_i      = (const int*)d_in[2];
    const int*   idx_j      = (const int*)d_in[3];
    const float* atom_mask  = (const float*)d_in[4];
    const float* batch_mask = (const float*)d_in[5];
    const float* a_coef     = (const float*)d_in[8];
    const float* a_exp      = (const float*)d_in[9];
    const float* phi_c      = (const float*)d_in[10];
    const float* phi_e      = (const float*)d_in[11];

    const int nA = in_sizes[0];
    const int nP = in_sizes[2];
    float* out = (float*)d_out;

    unsigned char* z8 = (unsigned char*)d_ws;   // 100 KB, ws ample

    zbl_k0<<<(nA + 255) / 256, 256, 0, stream>>>(an, z8, out, nA);

    const int nA_pad = (nA + 15) & ~15;
    const size_t smem = (size_t)nA_pad + 256 * sizeof(float);
    zbl_pair_kernel<<<NBLK, BLK, smem, stream>>>(
        disp, idx_i, idx_j, batch_mask, z8, a_coef, a_exp, phi_c, phi_e,
        out, nA, nP);

    zbl_epilogue<<<(nA + 255) / 256, 256, 0, stream>>>(out, atom_mask, nA);
}